// Round 18
// baseline (46.769 us; speedup 1.0000x reference)
//
#include <hip/hip_runtime.h>

constexpr int J_ = 31;
constexpr int UI = 131072;                 // 256*512 pairs

// Single fused kernel, no workspace. Block = 256 threads = 4 INDEPENDENT
// j-split waves; each wave owns one 16-pair tile and its own 6144 B LDS
// region (per-wave global_load_lds + per-wave vmcnt, NO __syncthreads).
// Escapes the ~16 single-wave-WG-slot/CU cap: LDS 24.6 KB/block -> 6
// blocks/CU x 4 waves = ~24 waves/CU potential (vs ~10 before).
//  - j-loop: lane g owns neighbors jb+g, h computed once per neighbor
//  - DPP quad all-reduce -> every lane holds full D[20]
//  - fused fit-MLP tail (4-lane split), weights from global (L1-hot)
constexpr int PPW   = 16;                  // pairs per wave
constexpr int WPB   = 4;                   // waves per block
constexpr int SGB   = PPW * 93 * 4;        // 5952 B per wave tile
constexpr int SGPAD = 6144;                // per-wave staged region
constexpr int NBLK  = UI / (PPW * WPB);    // 2048 blocks

typedef __attribute__((address_space(1))) const void g1void;
typedef __attribute__((address_space(3))) void s3void;

__device__ __forceinline__ float qsum(float x) {
    int a = __builtin_amdgcn_update_dpp(0, __float_as_int(x), 0xB1, 0xF, 0xF, true);
    x += __int_as_float(a);
    int b = __builtin_amdgcn_update_dpp(0, __float_as_int(x), 0x4E, 0xF, 0xF, true);
    x += __int_as_float(b);
    return x;
}

__global__ __launch_bounds__(WPB * 64) void dqn_all(
    const float* __restrict__ Sg,  const float* __restrict__ R,
    const float* __restrict__ W1,  const float* __restrict__ b1,
    const float* __restrict__ W2,  const float* __restrict__ b2,
    const float* __restrict__ Wf1, const float* __restrict__ bf1,
    const float* __restrict__ Wf2, const float* __restrict__ bf2,
    const float* __restrict__ Wf3, const float* __restrict__ bf3,
    float* __restrict__ out)
{
    __shared__ float4 sbuf4[WPB * SGPAD / 16];   // 24576 B
    const int tid  = threadIdx.x;
    const int wv   = tid >> 6;                   // wave 0..3
    const int lane = tid & 63;
    const int lp   = lane >> 2;                  // local pair 0..15
    const int g    = lane & 3;

    const int tile = blockIdx.x * WPB + wv;      // this wave's 16-pair tile
    const int pair = tile * PPW + lp;

    char* sb = reinterpret_cast<char*>(sbuf4) + wv * SGPAD;

    // ---- async stage this wave's Sg tile (6 x 1KB rounds, src-clamped) ----
    const char* gS = reinterpret_cast<const char*>(Sg) + (size_t)tile * SGB;
    #pragma unroll
    for (int r = 0; r < 6; ++r) {
        int byte = r * 1024 + lane * 16;
        if (byte > SGB - 16) byte = SGB - 16;    // dup reads; pad absorbs
        __builtin_amdgcn_global_load_lds((g1void*)(gS + byte),
                                         (s3void*)(sb + r * 1024), 16, 0, 0);
    }

    // Uniform embedding weights -> SGPRs
    float w10[10], w11[10], w12[10], c1w[10];
    #pragma unroll
    for (int p = 0; p < 10; ++p) {
        w10[p] = W1[p]; w11[p] = W1[10 + p]; w12[p] = W1[20 + p]; c1w[p] = b1[p];
    }

    // R row as float4[31]; lane g owns neighbors jb+g (8 named regs).
    const float4* rv = reinterpret_cast<const float4*>(R + (size_t)pair * 124);
    float4 r0 = rv[g];      float4 r1 = rv[4 + g];
    float4 r2 = rv[8 + g];  float4 r3 = rv[12 + g];
    float4 r4 = rv[16 + g]; float4 r5 = rv[20 + g];
    float4 r6 = rv[24 + g];
    int jt = 28 + g;
    float4 r7 = rv[jt < J_ ? jt : (J_ - 1)];     // clamped dup for g==3

    asm volatile("s_waitcnt vmcnt(0)" ::: "memory");   // this wave's Sg + R
    __builtin_amdgcn_sched_barrier(0);

    const float* sgL = reinterpret_cast<const float*>(sb) + lp * 93;

    float M0[10], M1[10], M2[10], M3[10];
    float4 Rs = {0.f, 0.f, 0.f, 0.f};
    #pragma unroll
    for (int p = 0; p < 10; ++p) { M0[p]=0.f; M1[p]=0.f; M2[p]=0.f; M3[p]=0.f; }

    auto PROC = [&](int j, const float4& r4v) {
        float s0 = sgL[j * 3 + 0];
        float s1 = sgL[j * 3 + 1];
        float s2 = sgL[j * 3 + 2];
        #pragma unroll
        for (int p = 0; p < 10; ++p) {
            float t = c1w[p] + s0 * w10[p] + s1 * w11[p] + s2 * w12[p];
            t = t > 0.f ? t : 0.f;     // ReLU, computed once per neighbor
            M0[p] += r4v.x * t;
            M1[p] += r4v.y * t;
            M2[p] += r4v.z * t;
            M3[p] += r4v.w * t;
        }
        Rs.x += r4v.x; Rs.y += r4v.y; Rs.z += r4v.z; Rs.w += r4v.w;
    };

    PROC(g,      r0); PROC(4 + g,  r1); PROC(8 + g,  r2); PROC(12 + g, r3);
    PROC(16 + g, r4); PROC(20 + g, r5); PROC(24 + g, r6);
    {   // tail j = 28+g; mask lane g==3 (j==31); LDS read stays in-buffer
        float m = (g < 3) ? 1.f : 0.f;
        float4 rm = {r7.x * m, r7.y * m, r7.z * m, r7.w * m};
        PROC(28 + g, rm);
    }

    // ---- quad all-reduce M[4][10], Rs (pure VALU DPP) ----
    #pragma unroll
    for (int p = 0; p < 10; ++p) {
        M0[p] = qsum(M0[p]); M1[p] = qsum(M1[p]);
        M2[p] = qsum(M2[p]); M3[p] = qsum(M3[p]);
    }
    Rs.x = qsum(Rs.x); Rs.y = qsum(Rs.y); Rs.z = qsum(Rs.z); Rs.w = qsum(Rs.w);

    float Mg[10];
    #pragma unroll
    for (int p = 0; p < 10; ++p)
        Mg[p] = (g == 0) ? M0[p] : (g == 1) ? M1[p] : (g == 2) ? M2[p] : M3[p];
    float Rsg = (g == 0) ? Rs.x : (g == 1) ? Rs.y : (g == 2) ? Rs.z : Rs.w;

    // T2 row g: T2g[n] = sum_p Mg[p]*W2[p][n] + Rsg*b2[n]   (uniform -> s_load)
    float T2g[10];
    #pragma unroll
    for (int n = 0; n < 10; ++n) T2g[n] = Rsg * b2[n];
    #pragma unroll
    for (int p = 0; p < 10; ++p) {
        float m = Mg[p];
        #pragma unroll
        for (int n = 0; n < 10; ++n) T2g[n] += m * W2[p * 10 + n];
    }

    // D[k*10+n] = sum over 4 lanes of T2g[k]*T2g[n]  (T1 == T2^T)
    float D[20];
    #pragma unroll
    for (int k = 0; k < 2; ++k)
        #pragma unroll
        for (int n = 0; n < 10; ++n) D[k * 10 + n] = T2g[k] * T2g[n];
    #pragma unroll
    for (int t = 0; t < 20; ++t) D[t] = qsum(D[t]);
    // Every lane now holds the full D[20] -> fused tail, no workspace.

    // ---- fit MLP 20->32->32->1, 4-lane split, weights global (L1-hot) ----
    float F[8];
    {
        const float4* b4 = reinterpret_cast<const float4*>(bf1 + g * 8);
        float4 x = b4[0], y = b4[1];
        F[0]=x.x; F[1]=x.y; F[2]=x.z; F[3]=x.w; F[4]=y.x; F[5]=y.y; F[6]=y.z; F[7]=y.w;
    }
    #pragma unroll
    for (int kk = 0; kk < 20; ++kk) {
        float d = D[kk];
        const float4* w4 = reinterpret_cast<const float4*>(Wf1 + kk * 32 + g * 8);
        float4 wa = w4[0], wb = w4[1];
        F[0] += d * wa.x; F[1] += d * wa.y; F[2] += d * wa.z; F[3] += d * wa.w;
        F[4] += d * wb.x; F[5] += d * wb.y; F[6] += d * wb.z; F[7] += d * wb.w;
    }
    #pragma unroll
    for (int i = 0; i < 8; ++i) F[i] = F[i] > 0.f ? F[i] : 0.f;

    // gather full f1 (static-index butterfly across the quad)
    float P[8];
    #pragma unroll
    for (int i = 0; i < 8; ++i) P[i] = __shfl_xor(F[i], 1);
    const bool odd = (g & 1);
    float lo[16];
    #pragma unroll
    for (int i = 0; i < 8; ++i) {
        lo[i]     = odd ? P[i] : F[i];
        lo[8 + i] = odd ? F[i] : P[i];
    }
    float hi[16];
    #pragma unroll
    for (int i = 0; i < 16; ++i) hi[i] = __shfl_xor(lo[i], 2);
    const bool up = (g & 2);
    float f1a[32];
    #pragma unroll
    for (int i = 0; i < 16; ++i) {
        f1a[i]      = up ? hi[i] : lo[i];
        f1a[16 + i] = up ? lo[i] : hi[i];
    }

    float G[8];
    {
        const float4* b4 = reinterpret_cast<const float4*>(bf2 + g * 8);
        float4 x = b4[0], y = b4[1];
        G[0]=x.x; G[1]=x.y; G[2]=x.z; G[3]=x.w; G[4]=y.x; G[5]=y.y; G[6]=y.z; G[7]=y.w;
    }
    #pragma unroll
    for (int kk = 0; kk < 32; ++kk) {
        float d = f1a[kk];
        const float4* w4 = reinterpret_cast<const float4*>(Wf2 + kk * 32 + g * 8);
        float4 wa = w4[0], wb = w4[1];
        G[0] += d * wa.x; G[1] += d * wa.y; G[2] += d * wa.z; G[3] += d * wa.w;
        G[4] += d * wb.x; G[5] += d * wb.y; G[6] += d * wb.z; G[7] += d * wb.w;
    }
    #pragma unroll
    for (int i = 0; i < 8; ++i) G[i] = G[i] > 0.f ? G[i] : 0.f;

    float qp;
    {
        const float4* w4 = reinterpret_cast<const float4*>(Wf3 + g * 8);
        float4 wa = w4[0], wb = w4[1];
        qp = G[0]*wa.x + G[1]*wa.y + G[2]*wa.z + G[3]*wa.w
           + G[4]*wb.x + G[5]*wb.y + G[6]*wb.z + G[7]*wb.w;
    }
    qp += __shfl_xor(qp, 1);
    qp += __shfl_xor(qp, 2);
    float q = qp + bf3[0];

    if (g == 0) out[pair] = q;
}

extern "C" void kernel_launch(void* const* d_in, const int* in_sizes, int n_in,
                              void* d_out, int out_size, void* d_ws, size_t ws_size,
                              hipStream_t stream) {
    const float* Sg  = (const float*)d_in[0];
    const float* R   = (const float*)d_in[1];
    const float* W1  = (const float*)d_in[2];
    const float* b1  = (const float*)d_in[3];
    const float* W2  = (const float*)d_in[4];
    const float* b2  = (const float*)d_in[5];
    const float* Wf1 = (const float*)d_in[6];
    const float* bf1 = (const float*)d_in[7];
    const float* Wf2 = (const float*)d_in[8];
    const float* bf2 = (const float*)d_in[9];
    const float* Wf3 = (const float*)d_in[10];
    const float* bf3 = (const float*)d_in[11];
    float* out = (float*)d_out;

    dqn_all<<<dim3(NBLK), dim3(WPB * 64), 0, stream>>>(
        Sg, R, W1, b1, W2, b2, Wf1, bf1, Wf2, bf2, Wf3, bf3, out);
}

// Round 19
// 46.449 us; speedup vs baseline: 1.0069x; 1.0069x over previous
//
#include <hip/hip_runtime.h>

constexpr int J_ = 31;
constexpr int UI = 131072;                 // 256*512 pairs
constexpr size_t D_BYTES = (size_t)UI * 20 * 4;   // 10.5 MB workspace

// ---------------- Phase 1: 2-tile pipelined j-split, W2 in LDS ---------------
// Block = 1 wave = 16 pairs x 4 lanes; 2 tiles per block (4096 blocks):
//   STAGE(Sg t0)+LOADR(t0); STAGE(Sg t1)+LOADR(t1)      [14+14 vmem]
//   vmcnt(14) -> t0 ready (t1 in flight) ; COMPUTE(t0)  [ends w/ 5 stores]
//   vmcnt(5)  -> t1 ready (stores linger); COMPUTE(t1)
// W2/b2 staged once to LDS (broadcast ds_read, no per-tile SMEM reload).
// D-store is branch-free (cndmask-selected values, 5 stores exactly).
constexpr int PPT   = 16;                  // pairs per tile
constexpr int TILES = 2;                   // tiles per block
constexpr int SGB   = PPT * 93 * 4;        // 5952 B
constexpr int SGPAD = 6144;                // staged region per buffer
constexpr int NBLK1 = UI / (PPT * TILES);  // 4096 blocks
constexpr int WOFF  = 2 * SGPAD / 4;       // float offset of W2 area (3072)

typedef __attribute__((address_space(1))) const void g1void;
typedef __attribute__((address_space(3))) void s3void;

__device__ __forceinline__ float qsum(float x) {
    int a = __builtin_amdgcn_update_dpp(0, __float_as_int(x), 0xB1, 0xF, 0xF, true);
    x += __int_as_float(a);
    int b = __builtin_amdgcn_update_dpp(0, __float_as_int(x), 0x4E, 0xF, 0xF, true);
    x += __int_as_float(b);
    return x;
}

__global__ __launch_bounds__(64) void dqn_phase1(
    const float* __restrict__ Sg, const float* __restrict__ R,
    const float* __restrict__ W1, const float* __restrict__ b1,
    const float* __restrict__ W2, const float* __restrict__ b2,
    float* __restrict__ Dws)
{
    __shared__ float4 sbuf4[(2 * SGPAD + 512) / 16];   // 2 bufs + W2/b2 area
    char*  sb  = reinterpret_cast<char*>(sbuf4);
    float* wl2 = reinterpret_cast<float*>(sbuf4) + WOFF;   // W2[100], b2[10]

    const int tid = threadIdx.x;           // == lane (single wave)
    const int lp  = tid >> 2;              // local pair 0..15
    const int g   = tid & 3;

    // ---- one-time: W2/b2 -> LDS (single wave, ds ordering handled) ----
    for (int i = tid; i < 100; i += 64) wl2[i] = W2[i];
    if (tid < 10) wl2[100 + tid] = b2[tid];

    // Uniform embedding weights -> SGPRs
    float w10[10], w11[10], w12[10], c1w[10];
    #pragma unroll
    for (int p = 0; p < 10; ++p) {
        w10[p] = W1[p]; w11[p] = W1[10 + p]; w12[p] = W1[20 + p]; c1w[p] = b1[p];
    }

    auto STAGE = [&](int tile, int off) {
        const char* gS = reinterpret_cast<const char*>(Sg) + (size_t)tile * SGB;
        #pragma unroll
        for (int r = 0; r < 6; ++r) {
            int byte = r * 1024 + tid * 16;
            if (byte > SGB - 16) byte = SGB - 16;      // dup; LDS pad absorbs
            __builtin_amdgcn_global_load_lds((g1void*)(gS + byte),
                                             (s3void*)(sb + off + r * 1024),
                                             16, 0, 0);
        }
    };

    auto LOADR = [&](int tile, float4& r0, float4& r1, float4& r2, float4& r3,
                     float4& r4, float4& r5, float4& r6, float4& r7) {
        const float4* rv = reinterpret_cast<const float4*>(
            R + (size_t)(tile * PPT + lp) * 124);
        r0 = rv[g];      r1 = rv[4 + g];  r2 = rv[8 + g];  r3 = rv[12 + g];
        r4 = rv[16 + g]; r5 = rv[20 + g]; r6 = rv[24 + g];
        int jt = 28 + g;
        r7 = rv[jt < J_ ? jt : (J_ - 1)];              // clamped dup for g==3
    };

    auto COMPUTE = [&](int off, int tileIdx,
                       float4 r0, float4 r1, float4 r2, float4 r3,
                       float4 r4, float4 r5, float4 r6, float4 r7) {
        const float* sgL = reinterpret_cast<const float*>(sb + off) + lp * 93;

        float M0[10], M1[10], M2[10], M3[10];
        float4 Rs = {0.f, 0.f, 0.f, 0.f};
        #pragma unroll
        for (int p = 0; p < 10; ++p) { M0[p]=0.f; M1[p]=0.f; M2[p]=0.f; M3[p]=0.f; }

        auto PROC = [&](int j, const float4& r4v) {
            float s0 = sgL[j * 3 + 0];
            float s1 = sgL[j * 3 + 1];
            float s2 = sgL[j * 3 + 2];
            #pragma unroll
            for (int p = 0; p < 10; ++p) {
                float t = c1w[p] + s0 * w10[p] + s1 * w11[p] + s2 * w12[p];
                t = t > 0.f ? t : 0.f;     // ReLU, once per neighbor
                M0[p] += r4v.x * t;
                M1[p] += r4v.y * t;
                M2[p] += r4v.z * t;
                M3[p] += r4v.w * t;
            }
            Rs.x += r4v.x; Rs.y += r4v.y; Rs.z += r4v.z; Rs.w += r4v.w;
        };

        PROC(g,      r0); PROC(4 + g,  r1); PROC(8 + g,  r2); PROC(12 + g, r3);
        PROC(16 + g, r4); PROC(20 + g, r5); PROC(24 + g, r6);
        {   // tail j = 28+g; mask lane g==3 (j==31)
            float m = (g < 3) ? 1.f : 0.f;
            float4 rm = {r7.x * m, r7.y * m, r7.z * m, r7.w * m};
            PROC(28 + g, rm);
        }

        // quad all-reduce (pure VALU DPP)
        #pragma unroll
        for (int p = 0; p < 10; ++p) {
            M0[p] = qsum(M0[p]); M1[p] = qsum(M1[p]);
            M2[p] = qsum(M2[p]); M3[p] = qsum(M3[p]);
        }
        Rs.x = qsum(Rs.x); Rs.y = qsum(Rs.y); Rs.z = qsum(Rs.z); Rs.w = qsum(Rs.w);

        float Mg[10];
        #pragma unroll
        for (int p = 0; p < 10; ++p)
            Mg[p] = (g == 0) ? M0[p] : (g == 1) ? M1[p] : (g == 2) ? M2[p] : M3[p];
        float Rsg = (g == 0) ? Rs.x : (g == 1) ? Rs.y : (g == 2) ? Rs.z : Rs.w;

        // T2 row g from LDS-resident W2/b2 (broadcast reads, conflict-free)
        float T2g[10];
        #pragma unroll
        for (int n = 0; n < 10; ++n) T2g[n] = Rsg * wl2[100 + n];
        #pragma unroll
        for (int p = 0; p < 10; ++p) {
            float m = Mg[p];
            #pragma unroll
            for (int n = 0; n < 10; ++n) T2g[n] += m * wl2[p * 10 + n];
        }

        // D[k*10+n] = sum over 4 lanes of T2g[k]*T2g[n]  (T1 == T2^T)
        float D[20];
        #pragma unroll
        for (int k = 0; k < 2; ++k)
            #pragma unroll
            for (int n = 0; n < 10; ++n) D[k * 10 + n] = T2g[k] * T2g[n];
        #pragma unroll
        for (int t = 0; t < 20; ++t) D[t] = qsum(D[t]);

        // Branch-free transposed store: lane g stores D[5g .. 5g+4]
        // (values selected by static cndmask chains -> exactly 5 stores)
        float s0 = (g == 0) ? D[0] : (g == 1) ? D[5]  : (g == 2) ? D[10] : D[15];
        float s1 = (g == 0) ? D[1] : (g == 1) ? D[6]  : (g == 2) ? D[11] : D[16];
        float s2 = (g == 0) ? D[2] : (g == 1) ? D[7]  : (g == 2) ? D[12] : D[17];
        float s3 = (g == 0) ? D[3] : (g == 1) ? D[8]  : (g == 2) ? D[13] : D[18];
        float s4 = (g == 0) ? D[4] : (g == 1) ? D[9]  : (g == 2) ? D[14] : D[19];
        float* dw = Dws + (size_t)(g * 5) * UI + tileIdx * PPT + lp;
        dw[0 * UI] = s0; dw[1 * UI] = s1; dw[2 * UI] = s2;
        dw[3 * UI] = s3; dw[4 * UI] = s4;
    };

    // ---- 2-tile pipeline, counted vmcnt ----
    const int t0 = blockIdx.x * TILES;
    float4 pA0,pA1,pA2,pA3,pA4,pA5,pA6,pA7;
    float4 pB0,pB1,pB2,pB3,pB4,pB5,pB6,pB7;

    STAGE(t0 + 0, 0);     LOADR(t0 + 0, pA0,pA1,pA2,pA3,pA4,pA5,pA6,pA7);
    STAGE(t0 + 1, SGPAD); LOADR(t0 + 1, pB0,pB1,pB2,pB3,pB4,pB5,pB6,pB7);
    asm volatile("s_waitcnt vmcnt(14)" ::: "memory");   // tile0 ready
    __builtin_amdgcn_sched_barrier(0);
    COMPUTE(0, t0 + 0, pA0,pA1,pA2,pA3,pA4,pA5,pA6,pA7);   // +5 stores
    asm volatile("s_waitcnt vmcnt(5)" ::: "memory");    // tile1 ready
    __builtin_amdgcn_sched_barrier(0);
    COMPUTE(SGPAD, t0 + 1, pB0,pB1,pB2,pB3,pB4,pB5,pB6,pB7);
}

// ---------------- Phase 2: fit MLP, 4 lanes/pair (proven r12 tail) -----------
__global__ __launch_bounds__(256) void dqn_phase2(
    const float* __restrict__ Dws,
    const float* __restrict__ Wf1, const float* __restrict__ bf1,
    const float* __restrict__ Wf2, const float* __restrict__ bf2,
    const float* __restrict__ Wf3, const float* __restrict__ bf3,
    float* __restrict__ out)
{
    __shared__ float4 wlds4[448];          // 7168 B
    const int tid = threadIdx.x;

    {
        if (tid < 160) wlds4[tid] = reinterpret_cast<const float4*>(Wf1)[tid];
        wlds4[160 + tid] = reinterpret_cast<const float4*>(Wf2)[tid];
        if (tid < 8)       wlds4[416 + tid]        = reinterpret_cast<const float4*>(bf1)[tid];
        else if (tid < 16) wlds4[424 + (tid - 8)]  = reinterpret_cast<const float4*>(bf2)[tid - 8];
        else if (tid < 24) wlds4[432 + (tid - 16)] = reinterpret_cast<const float4*>(Wf3)[tid - 16];
        else if (tid == 24) { reinterpret_cast<float*>(wlds4)[1760] = bf3[0]; }
    }
    __syncthreads();

    const int gt   = blockIdx.x * 256 + tid;
    const int pair = gt >> 2;
    const int g    = gt & 3;

    float D[20];
    #pragma unroll
    for (int t = 0; t < 20; ++t) D[t] = Dws[(size_t)t * UI + pair];  // coalesced

    const float* wl = reinterpret_cast<const float*>(wlds4);

    float F[8];
    {
        const float4* b4 = reinterpret_cast<const float4*>(wl + 1664 + g * 8);
        float4 x = b4[0], y = b4[1];
        F[0]=x.x; F[1]=x.y; F[2]=x.z; F[3]=x.w; F[4]=y.x; F[5]=y.y; F[6]=y.z; F[7]=y.w;
    }
    #pragma unroll
    for (int kk = 0; kk < 20; ++kk) {
        float d = D[kk];
        const float4* w4 = reinterpret_cast<const float4*>(wl + kk * 32 + g * 8);
        float4 wa = w4[0], wb = w4[1];
        F[0] += d * wa.x; F[1] += d * wa.y; F[2] += d * wa.z; F[3] += d * wa.w;
        F[4] += d * wb.x; F[5] += d * wb.y; F[6] += d * wb.z; F[7] += d * wb.w;
    }
    #pragma unroll
    for (int i = 0; i < 8; ++i) F[i] = F[i] > 0.f ? F[i] : 0.f;

    float P[8];
    #pragma unroll
    for (int i = 0; i < 8; ++i) P[i] = __shfl_xor(F[i], 1);
    const bool odd = (g & 1);
    float lo[16];
    #pragma unroll
    for (int i = 0; i < 8; ++i) {
        lo[i]     = odd ? P[i] : F[i];
        lo[8 + i] = odd ? F[i] : P[i];
    }
    float hi[16];
    #pragma unroll
    for (int i = 0; i < 16; ++i) hi[i] = __shfl_xor(lo[i], 2);
    const bool up = (g & 2);
    float f1a[32];
    #pragma unroll
    for (int i = 0; i < 16; ++i) {
        f1a[i]      = up ? hi[i] : lo[i];
        f1a[16 + i] = up ? lo[i] : hi[i];
    }

    float G[8];
    {
        const float4* b4 = reinterpret_cast<const float4*>(wl + 1696 + g * 8);
        float4 x = b4[0], y = b4[1];
        G[0]=x.x; G[1]=x.y; G[2]=x.z; G[3]=x.w; G[4]=y.x; G[5]=y.y; G[6]=y.z; G[7]=y.w;
    }
    #pragma unroll
    for (int kk = 0; kk < 32; ++kk) {
        float d = f1a[kk];
        const float4* w4 = reinterpret_cast<const float4*>(wl + 640 + kk * 32 + g * 8);
        float4 wa = w4[0], wb = w4[1];
        G[0] += d * wa.x; G[1] += d * wa.y; G[2] += d * wa.z; G[3] += d * wa.w;
        G[4] += d * wb.x; G[5] += d * wb.y; G[6] += d * wb.z; G[7] += d * wb.w;
    }
    #pragma unroll
    for (int i = 0; i < 8; ++i) G[i] = G[i] > 0.f ? G[i] : 0.f;

    float qp;
    {
        const float4* w4 = reinterpret_cast<const float4*>(wl + 1728 + g * 8);
        float4 wa = w4[0], wb = w4[1];
        qp = G[0]*wa.x + G[1]*wa.y + G[2]*wa.z + G[3]*wa.w
           + G[4]*wb.x + G[5]*wb.y + G[6]*wb.z + G[7]*wb.w;
    }
    qp += __shfl_xor(qp, 1);
    qp += __shfl_xor(qp, 2);
    float q = qp + wl[1760];

    if (g == 0) out[pair] = q;
}

// ---------------- Fallback: known-good fused v1 (if ws too small) ------------
struct Nb1 { float s0, s1, s2; float4 r; };
__device__ __forceinline__ Nb1 load_nb1(const float* __restrict__ sg,
                                        const float* __restrict__ rr, int j) {
    Nb1 d;
    d.s0 = sg[j * 3 + 0]; d.s1 = sg[j * 3 + 1]; d.s2 = sg[j * 3 + 2];
    d.r = *reinterpret_cast<const float4*>(rr + j * 4);
    return d;
}
__global__ __launch_bounds__(256, 2) void dqn_fused_fb(
    const float* __restrict__ Sg,  const float* __restrict__ R,
    const float* __restrict__ W1,  const float* __restrict__ b1,
    const float* __restrict__ W2,  const float* __restrict__ b2,
    const float* __restrict__ Wf1, const float* __restrict__ bf1,
    const float* __restrict__ Wf2, const float* __restrict__ bf2,
    const float* __restrict__ Wf3, const float* __restrict__ bf3,
    float* __restrict__ out)
{
    const int pair = blockIdx.x * 256 + threadIdx.x;
    const float* sg = Sg + (size_t)pair * (J_ * 3);
    const float* rr = R  + (size_t)pair * (J_ * 4);
    float w1[3][10], c1[10];
    #pragma unroll
    for (int k = 0; k < 3; ++k)
        #pragma unroll
        for (int p = 0; p < 10; ++p) w1[k][p] = W1[k * 10 + p];
    #pragma unroll
    for (int p = 0; p < 10; ++p) c1[p] = b1[p];
    float M[4][10]; float Rs[4] = {0.f,0.f,0.f,0.f};
    #pragma unroll
    for (int l = 0; l < 4; ++l)
        #pragma unroll
        for (int p = 0; p < 10; ++p) M[l][p] = 0.f;
    #pragma unroll 1
    for (int j = 0; j < J_; ++j) {
        Nb1 nb = load_nb1(sg, rr, j);
        float h[10];
        #pragma unroll
        for (int p = 0; p < 10; ++p) {
            float t = c1[p] + nb.s0*w1[0][p] + nb.s1*w1[1][p] + nb.s2*w1[2][p];
            h[p] = t > 0.f ? t : 0.f;
        }
        Rs[0]+=nb.r.x; Rs[1]+=nb.r.y; Rs[2]+=nb.r.z; Rs[3]+=nb.r.w;
        #pragma unroll
        for (int p = 0; p < 10; ++p) {
            M[0][p]+=nb.r.x*h[p]; M[1][p]+=nb.r.y*h[p];
            M[2][p]+=nb.r.z*h[p]; M[3][p]+=nb.r.w*h[p];
        }
    }
    float T2[4][10];
    #pragma unroll
    for (int l = 0; l < 4; ++l)
        #pragma unroll
        for (int n = 0; n < 10; ++n) T2[l][n] = Rs[l] * b2[n];
    #pragma unroll
    for (int p = 0; p < 10; ++p) {
        #pragma unroll
        for (int l = 0; l < 4; ++l) {
            float m = M[l][p];
            #pragma unroll
            for (int n = 0; n < 10; ++n) T2[l][n] += m * W2[p * 10 + n];
        }
    }
    float D[20];
    #pragma unroll
    for (int k = 0; k < 2; ++k)
        #pragma unroll
        for (int n = 0; n < 10; ++n)
            D[k*10+n] = T2[0][k]*T2[0][n] + T2[1][k]*T2[1][n]
                      + T2[2][k]*T2[2][n] + T2[3][k]*T2[3][n];
    float f1[32];
    #pragma unroll
    for (int o = 0; o < 32; ++o) f1[o] = bf1[o];
    #pragma unroll
    for (int kk = 0; kk < 20; ++kk) {
        const float4* wrow = reinterpret_cast<const float4*>(Wf1 + kk * 32);
        float d = D[kk];
        #pragma unroll
        for (int v = 0; v < 8; ++v) {
            float4 w = wrow[v];
            f1[4*v+0]+=d*w.x; f1[4*v+1]+=d*w.y; f1[4*v+2]+=d*w.z; f1[4*v+3]+=d*w.w;
        }
    }
    #pragma unroll
    for (int o = 0; o < 32; ++o) f1[o] = f1[o] > 0.f ? f1[o] : 0.f;
    float f2[32];
    #pragma unroll
    for (int o = 0; o < 32; ++o) f2[o] = bf2[o];
    #pragma unroll
    for (int kk = 0; kk < 32; ++kk) {
        const float4* wrow = reinterpret_cast<const float4*>(Wf2 + kk * 32);
        float d = f1[kk];
        #pragma unroll
        for (int v = 0; v < 8; ++v) {
            float4 w = wrow[v];
            f2[4*v+0]+=d*w.x; f2[4*v+1]+=d*w.y; f2[4*v+2]+=d*w.z; f2[4*v+3]+=d*w.w;
        }
    }
    #pragma unroll
    for (int o = 0; o < 32; ++o) f2[o] = f2[o] > 0.f ? f2[o] : 0.f;
    float q = bf3[0];
    #pragma unroll
    for (int o = 0; o < 32; o += 4) {
        float4 w = *reinterpret_cast<const float4*>(Wf3 + o);
        q += f2[o+0]*w.x + f2[o+1]*w.y + f2[o+2]*w.z + f2[o+3]*w.w;
    }
    out[pair] = q;
}

extern "C" void kernel_launch(void* const* d_in, const int* in_sizes, int n_in,
                              void* d_out, int out_size, void* d_ws, size_t ws_size,
                              hipStream_t stream) {
    const float* Sg  = (const float*)d_in[0];
    const float* R   = (const float*)d_in[1];
    const float* W1  = (const float*)d_in[2];
    const float* b1  = (const float*)d_in[3];
    const float* W2  = (const float*)d_in[4];
    const float* b2  = (const float*)d_in[5];
    const float* Wf1 = (const float*)d_in[6];
    const float* bf1 = (const float*)d_in[7];
    const float* Wf2 = (const float*)d_in[8];
    const float* bf2 = (const float*)d_in[9];
    const float* Wf3 = (const float*)d_in[10];
    const float* bf3 = (const float*)d_in[11];
    float* out = (float*)d_out;

    if (ws_size >= D_BYTES) {
        float* Dws = (float*)d_ws;
        dqn_phase1<<<dim3(NBLK1), dim3(64), 0, stream>>>(
            Sg, R, W1, b1, W2, b2, Dws);
        dqn_phase2<<<dim3((UI * 4) / 256), dim3(256), 0, stream>>>(
            Dws, Wf1, bf1, Wf2, bf2, Wf3, bf3, out);
    } else {
        dqn_fused_fb<<<dim3(UI / 256), dim3(256), 0, stream>>>(
            Sg, R, W1, b1, W2, b2, Wf1, bf1, Wf2, bf2, Wf3, bf3, out);
    }
}

// Round 20
// 42.939 us; speedup vs baseline: 1.0892x; 1.0817x over previous
//
#include <hip/hip_runtime.h>

constexpr int J_ = 31;
constexpr int UI = 131072;                 // 256*512 pairs
constexpr size_t D_BYTES = (size_t)UI * 20 * 4;   // 10.5 MB workspace

// ---------------- Phase 1: ZERO-LDS j-split, all-register prefetch -----------
// Block = 1 wave = 16 pairs x 4 lanes. No LDS at all (max WG-slot residency).
// Lane g of pair lp owns neighbors j = 4b+g. Prefetch up front:
//   Sg: 24 scalar dwords (quad reads 48B line-contiguous per j-block)
//   R : 8 float4 (j-split)
// one vmcnt(0), then pure-VALU compute: h once per neighbor, DPP quad
// all-reduce, T2 (uniform W2 -> s_load), D, branch-free 5-store.
constexpr int PPB   = 16;
constexpr int NBLK1 = UI / PPB;            // 8192 blocks

__device__ __forceinline__ float qsum(float x) {
    int a = __builtin_amdgcn_update_dpp(0, __float_as_int(x), 0xB1, 0xF, 0xF, true);
    x += __int_as_float(a);
    int b = __builtin_amdgcn_update_dpp(0, __float_as_int(x), 0x4E, 0xF, 0xF, true);
    x += __int_as_float(b);
    return x;
}

__global__ __launch_bounds__(64) void dqn_phase1(
    const float* __restrict__ Sg, const float* __restrict__ R,
    const float* __restrict__ W1, const float* __restrict__ b1,
    const float* __restrict__ W2, const float* __restrict__ b2,
    float* __restrict__ Dws)
{
    const int tid  = threadIdx.x;          // == lane (single wave)
    const int lp   = tid >> 2;             // local pair 0..15
    const int g    = tid & 3;
    const int pair = blockIdx.x * PPB + lp;

    // Uniform embedding weights -> SGPRs
    float w10[10], w11[10], w12[10], c1w[10];
    #pragma unroll
    for (int p = 0; p < 10; ++p) {
        w10[p] = W1[p]; w11[p] = W1[10 + p]; w12[p] = W1[20 + p]; c1w[p] = b1[p];
    }

    // ---- register prefetch: Sg (24 dwords) + R (8 float4), one wait ----
    const float* sgp = Sg + (size_t)pair * 93 + 3 * g;   // lane's j=4b+g base
    float sA[8][3];
    #pragma unroll
    for (int b = 0; b < 8; ++b) {
        int idx = 12 * b;                                // + 3g folded in sgp
        if (b == 7 && g == 3) idx = 90 - 3 * g + 12 * 0; // clamp j=31 -> dup row floats 90..92
        // (for b==7,g==3: absolute = pair*93 + 90; masked later)
        const float* sp = (b == 7 && g == 3) ? (Sg + (size_t)pair * 93 + 90) : (sgp + idx);
        sA[b][0] = sp[0]; sA[b][1] = sp[1]; sA[b][2] = sp[2];
    }

    const float4* rv = reinterpret_cast<const float4*>(R + (size_t)pair * 124);
    float4 r0 = rv[g];      float4 r1 = rv[4 + g];
    float4 r2 = rv[8 + g];  float4 r3 = rv[12 + g];
    float4 r4 = rv[16 + g]; float4 r5 = rv[20 + g];
    float4 r6 = rv[24 + g];
    int jt = 28 + g;
    float4 r7 = rv[jt < J_ ? jt : (J_ - 1)];             // clamped dup for g==3

    asm volatile("s_waitcnt vmcnt(0)" ::: "memory");
    __builtin_amdgcn_sched_barrier(0);

    float M0[10], M1[10], M2[10], M3[10];
    float4 Rs = {0.f, 0.f, 0.f, 0.f};
    #pragma unroll
    for (int p = 0; p < 10; ++p) { M0[p]=0.f; M1[p]=0.f; M2[p]=0.f; M3[p]=0.f; }

    auto PROC = [&](float s0, float s1, float s2, const float4& r4v) {
        #pragma unroll
        for (int p = 0; p < 10; ++p) {
            float t = c1w[p] + s0 * w10[p] + s1 * w11[p] + s2 * w12[p];
            t = t > 0.f ? t : 0.f;         // ReLU, once per neighbor
            M0[p] += r4v.x * t;
            M1[p] += r4v.y * t;
            M2[p] += r4v.z * t;
            M3[p] += r4v.w * t;
        }
        Rs.x += r4v.x; Rs.y += r4v.y; Rs.z += r4v.z; Rs.w += r4v.w;
    };

    PROC(sA[0][0], sA[0][1], sA[0][2], r0);
    PROC(sA[1][0], sA[1][1], sA[1][2], r1);
    PROC(sA[2][0], sA[2][1], sA[2][2], r2);
    PROC(sA[3][0], sA[3][1], sA[3][2], r3);
    PROC(sA[4][0], sA[4][1], sA[4][2], r4);
    PROC(sA[5][0], sA[5][1], sA[5][2], r5);
    PROC(sA[6][0], sA[6][1], sA[6][2], r6);
    {   // tail j = 28+g; mask lane g==3 (j==31)
        float m = (g < 3) ? 1.f : 0.f;
        float4 rm = {r7.x * m, r7.y * m, r7.z * m, r7.w * m};
        PROC(sA[7][0], sA[7][1], sA[7][2], rm);
    }

    // ---- quad all-reduce M[4][10], Rs (pure VALU DPP) ----
    #pragma unroll
    for (int p = 0; p < 10; ++p) {
        M0[p] = qsum(M0[p]); M1[p] = qsum(M1[p]);
        M2[p] = qsum(M2[p]); M3[p] = qsum(M3[p]);
    }
    Rs.x = qsum(Rs.x); Rs.y = qsum(Rs.y); Rs.z = qsum(Rs.z); Rs.w = qsum(Rs.w);

    float Mg[10];
    #pragma unroll
    for (int p = 0; p < 10; ++p)
        Mg[p] = (g == 0) ? M0[p] : (g == 1) ? M1[p] : (g == 2) ? M2[p] : M3[p];
    float Rsg = (g == 0) ? Rs.x : (g == 1) ? Rs.y : (g == 2) ? Rs.z : Rs.w;

    // T2 row g: T2g[n] = sum_p Mg[p]*W2[p][n] + Rsg*b2[n]   (uniform -> s_load)
    float T2g[10];
    #pragma unroll
    for (int n = 0; n < 10; ++n) T2g[n] = Rsg * b2[n];
    #pragma unroll
    for (int p = 0; p < 10; ++p) {
        float m = Mg[p];
        #pragma unroll
        for (int n = 0; n < 10; ++n) T2g[n] += m * W2[p * 10 + n];
    }

    // D[k*10+n] = sum over 4 lanes of T2g[k]*T2g[n]  (T1 == T2^T)
    float D[20];
    #pragma unroll
    for (int k = 0; k < 2; ++k)
        #pragma unroll
        for (int n = 0; n < 10; ++n) D[k * 10 + n] = T2g[k] * T2g[n];
    #pragma unroll
    for (int t = 0; t < 20; ++t) D[t] = qsum(D[t]);

    // Branch-free transposed store: lane g stores D[5g .. 5g+4]
    float s0 = (g == 0) ? D[0] : (g == 1) ? D[5]  : (g == 2) ? D[10] : D[15];
    float s1 = (g == 0) ? D[1] : (g == 1) ? D[6]  : (g == 2) ? D[11] : D[16];
    float s2 = (g == 0) ? D[2] : (g == 1) ? D[7]  : (g == 2) ? D[12] : D[17];
    float s3 = (g == 0) ? D[3] : (g == 1) ? D[8]  : (g == 2) ? D[13] : D[18];
    float s4 = (g == 0) ? D[4] : (g == 1) ? D[9]  : (g == 2) ? D[14] : D[19];
    float* dw = Dws + (size_t)(g * 5) * UI + pair;
    dw[0 * UI] = s0; dw[1 * UI] = s1; dw[2 * UI] = s2;
    dw[3 * UI] = s3; dw[4 * UI] = s4;
}

// ---------------- Phase 2: fit MLP, 4 lanes/pair (proven r12 tail) -----------
__global__ __launch_bounds__(256) void dqn_phase2(
    const float* __restrict__ Dws,
    const float* __restrict__ Wf1, const float* __restrict__ bf1,
    const float* __restrict__ Wf2, const float* __restrict__ bf2,
    const float* __restrict__ Wf3, const float* __restrict__ bf3,
    float* __restrict__ out)
{
    __shared__ float4 wlds4[448];          // 7168 B
    const int tid = threadIdx.x;

    {
        if (tid < 160) wlds4[tid] = reinterpret_cast<const float4*>(Wf1)[tid];
        wlds4[160 + tid] = reinterpret_cast<const float4*>(Wf2)[tid];
        if (tid < 8)       wlds4[416 + tid]        = reinterpret_cast<const float4*>(bf1)[tid];
        else if (tid < 16) wlds4[424 + (tid - 8)]  = reinterpret_cast<const float4*>(bf2)[tid - 8];
        else if (tid < 24) wlds4[432 + (tid - 16)] = reinterpret_cast<const float4*>(Wf3)[tid - 16];
        else if (tid == 24) { reinterpret_cast<float*>(wlds4)[1760] = bf3[0]; }
    }
    __syncthreads();

    const int gt   = blockIdx.x * 256 + tid;
    const int pair = gt >> 2;
    const int g    = gt & 3;

    float D[20];
    #pragma unroll
    for (int t = 0; t < 20; ++t) D[t] = Dws[(size_t)t * UI + pair];  // coalesced

    const float* wl = reinterpret_cast<const float*>(wlds4);

    float F[8];
    {
        const float4* b4 = reinterpret_cast<const float4*>(wl + 1664 + g * 8);
        float4 x = b4[0], y = b4[1];
        F[0]=x.x; F[1]=x.y; F[2]=x.z; F[3]=x.w; F[4]=y.x; F[5]=y.y; F[6]=y.z; F[7]=y.w;
    }
    #pragma unroll
    for (int kk = 0; kk < 20; ++kk) {
        float d = D[kk];
        const float4* w4 = reinterpret_cast<const float4*>(wl + kk * 32 + g * 8);
        float4 wa = w4[0], wb = w4[1];
        F[0] += d * wa.x; F[1] += d * wa.y; F[2] += d * wa.z; F[3] += d * wa.w;
        F[4] += d * wb.x; F[5] += d * wb.y; F[6] += d * wb.z; F[7] += d * wb.w;
    }
    #pragma unroll
    for (int i = 0; i < 8; ++i) F[i] = F[i] > 0.f ? F[i] : 0.f;

    float P[8];
    #pragma unroll
    for (int i = 0; i < 8; ++i) P[i] = __shfl_xor(F[i], 1);
    const bool odd = (g & 1);
    float lo[16];
    #pragma unroll
    for (int i = 0; i < 8; ++i) {
        lo[i]     = odd ? P[i] : F[i];
        lo[8 + i] = odd ? F[i] : P[i];
    }
    float hi[16];
    #pragma unroll
    for (int i = 0; i < 16; ++i) hi[i] = __shfl_xor(lo[i], 2);
    const bool up = (g & 2);
    float f1a[32];
    #pragma unroll
    for (int i = 0; i < 16; ++i) {
        f1a[i]      = up ? hi[i] : lo[i];
        f1a[16 + i] = up ? lo[i] : hi[i];
    }

    float G[8];
    {
        const float4* b4 = reinterpret_cast<const float4*>(wl + 1696 + g * 8);
        float4 x = b4[0], y = b4[1];
        G[0]=x.x; G[1]=x.y; G[2]=x.z; G[3]=x.w; G[4]=y.x; G[5]=y.y; G[6]=y.z; G[7]=y.w;
    }
    #pragma unroll
    for (int kk = 0; kk < 32; ++kk) {
        float d = f1a[kk];
        const float4* w4 = reinterpret_cast<const float4*>(wl + 640 + kk * 32 + g * 8);
        float4 wa = w4[0], wb = w4[1];
        G[0] += d * wa.x; G[1] += d * wa.y; G[2] += d * wa.z; G[3] += d * wa.w;
        G[4] += d * wb.x; G[5] += d * wb.y; G[6] += d * wb.z; G[7] += d * wb.w;
    }
    #pragma unroll
    for (int i = 0; i < 8; ++i) G[i] = G[i] > 0.f ? G[i] : 0.f;

    float qp;
    {
        const float4* w4 = reinterpret_cast<const float4*>(wl + 1728 + g * 8);
        float4 wa = w4[0], wb = w4[1];
        qp = G[0]*wa.x + G[1]*wa.y + G[2]*wa.z + G[3]*wa.w
           + G[4]*wb.x + G[5]*wb.y + G[6]*wb.z + G[7]*wb.w;
    }
    qp += __shfl_xor(qp, 1);
    qp += __shfl_xor(qp, 2);
    float q = qp + wl[1760];

    if (g == 0) out[pair] = q;
}

// ---------------- Fallback: known-good fused v1 (if ws too small) ------------
struct Nb1 { float s0, s1, s2; float4 r; };
__device__ __forceinline__ Nb1 load_nb1(const float* __restrict__ sg,
                                        const float* __restrict__ rr, int j) {
    Nb1 d;
    d.s0 = sg[j * 3 + 0]; d.s1 = sg[j * 3 + 1]; d.s2 = sg[j * 3 + 2];
    d.r = *reinterpret_cast<const float4*>(rr + j * 4);
    return d;
}
__global__ __launch_bounds__(256, 2) void dqn_fused_fb(
    const float* __restrict__ Sg,  const float* __restrict__ R,
    const float* __restrict__ W1,  const float* __restrict__ b1,
    const float* __restrict__ W2,  const float* __restrict__ b2,
    const float* __restrict__ Wf1, const float* __restrict__ bf1,
    const float* __restrict__ Wf2, const float* __restrict__ bf2,
    const float* __restrict__ Wf3, const float* __restrict__ bf3,
    float* __restrict__ out)
{
    const int pair = blockIdx.x * 256 + threadIdx.x;
    const float* sg = Sg + (size_t)pair * (J_ * 3);
    const float* rr = R  + (size_t)pair * (J_ * 4);
    float w1[3][10], c1[10];
    #pragma unroll
    for (int k = 0; k < 3; ++k)
        #pragma unroll
        for (int p = 0; p < 10; ++p) w1[k][p] = W1[k * 10 + p];
    #pragma unroll
    for (int p = 0; p < 10; ++p) c1[p] = b1[p];
    float M[4][10]; float Rs[4] = {0.f,0.f,0.f,0.f};
    #pragma unroll
    for (int l = 0; l < 4; ++l)
        #pragma unroll
        for (int p = 0; p < 10; ++p) M[l][p] = 0.f;
    #pragma unroll 1
    for (int j = 0; j < J_; ++j) {
        Nb1 nb = load_nb1(sg, rr, j);
        float h[10];
        #pragma unroll
        for (int p = 0; p < 10; ++p) {
            float t = c1[p] + nb.s0*w1[0][p] + nb.s1*w1[1][p] + nb.s2*w1[2][p];
            h[p] = t > 0.f ? t : 0.f;
        }
        Rs[0]+=nb.r.x; Rs[1]+=nb.r.y; Rs[2]+=nb.r.z; Rs[3]+=nb.r.w;
        #pragma unroll
        for (int p = 0; p < 10; ++p) {
            M[0][p]+=nb.r.x*h[p]; M[1][p]+=nb.r.y*h[p];
            M[2][p]+=nb.r.z*h[p]; M[3][p]+=nb.r.w*h[p];
        }
    }
    float T2[4][10];
    #pragma unroll
    for (int l = 0; l < 4; ++l)
        #pragma unroll
        for (int n = 0; n < 10; ++n) T2[l][n] = Rs[l] * b2[n];
    #pragma unroll
    for (int p = 0; p < 10; ++p) {
        #pragma unroll
        for (int l = 0; l < 4; ++l) {
            float m = M[l][p];
            #pragma unroll
            for (int n = 0; n < 10; ++n) T2[l][n] += m * W2[p * 10 + n];
        }
    }
    float D[20];
    #pragma unroll
    for (int k = 0; k < 2; ++k)
        #pragma unroll
        for (int n = 0; n < 10; ++n)
            D[k*10+n] = T2[0][k]*T2[0][n] + T2[1][k]*T2[1][n]
                      + T2[2][k]*T2[2][n] + T2[3][k]*T2[3][n];
    float f1[32];
    #pragma unroll
    for (int o = 0; o < 32; ++o) f1[o] = bf1[o];
    #pragma unroll
    for (int kk = 0; kk < 20; ++kk) {
        const float4* wrow = reinterpret_cast<const float4*>(Wf1 + kk * 32);
        float d = D[kk];
        #pragma unroll
        for (int v = 0; v < 8; ++v) {
            float4 w = wrow[v];
            f1[4*v+0]+=d*w.x; f1[4*v+1]+=d*w.y; f1[4*v+2]+=d*w.z; f1[4*v+3]+=d*w.w;
        }
    }
    #pragma unroll
    for (int o = 0; o < 32; ++o) f1[o] = f1[o] > 0.f ? f1[o] : 0.f;
    float f2[32];
    #pragma unroll
    for (int o = 0; o < 32; ++o) f2[o] = bf2[o];
    #pragma unroll
    for (int kk = 0; kk < 32; ++kk) {
        const float4* wrow = reinterpret_cast<const float4*>(Wf2 + kk * 32);
        float d = f1[kk];
        #pragma unroll
        for (int v = 0; v < 8; ++v) {
            float4 w = wrow[v];
            f2[4*v+0]+=d*w.x; f2[4*v+1]+=d*w.y; f2[4*v+2]+=d*w.z; f2[4*v+3]+=d*w.w;
        }
    }
    #pragma unroll
    for (int o = 0; o < 32; ++o) f2[o] = f2[o] > 0.f ? f2[o] : 0.f;
    float q = bf3[0];
    #pragma unroll
    for (int o = 0; o < 32; o += 4) {
        float4 w = *reinterpret_cast<const float4*>(Wf3 + o);
        q += f2[o+0]*w.x + f2[o+1]*w.y + f2[o+2]*w.z + f2[o+3]*w.w;
    }
    out[pair] = q;
}

extern "C" void kernel_launch(void* const* d_in, const int* in_sizes, int n_in,
                              void* d_out, int out_size, void* d_ws, size_t ws_size,
                              hipStream_t stream) {
    const float* Sg  = (const float*)d_in[0];
    const float* R   = (const float*)d_in[1];
    const float* W1  = (const float*)d_in[2];
    const float* b1  = (const float*)d_in[3];
    const float* W2  = (const float*)d_in[4];
    const float* b2  = (const float*)d_in[5];
    const float* Wf1 = (const float*)d_in[6];
    const float* bf1 = (const float*)d_in[7];
    const float* Wf2 = (const float*)d_in[8];
    const float* bf2 = (const float*)d_in[9];
    const float* Wf3 = (const float*)d_in[10];
    const float* bf3 = (const float*)d_in[11];
    float* out = (float*)d_out;

    if (ws_size >= D_BYTES) {
        float* Dws = (float*)d_ws;
        dqn_phase1<<<dim3(NBLK1), dim3(64), 0, stream>>>(
            Sg, R, W1, b1, W2, b2, Dws);
        dqn_phase2<<<dim3((UI * 4) / 256), dim3(256), 0, stream>>>(
            Dws, Wf1, bf1, Wf2, bf2, Wf3, bf3, out);
    } else {
        dqn_fused_fb<<<dim3(UI / 256), dim3(256), 0, stream>>>(
            Sg, R, W1, b1, W2, b2, Wf1, bf1, Wf2, bf2, Wf3, bf3, out);
    }
}